// Round 5
// baseline (533.758 us; speedup 1.0000x reference)
//
#include <hip/hip_runtime.h>
#include <math.h>

#define C 512
#define K 256
#define HW 160
#define NPIX (HW*HW)   // 25600
#define PW 162
#define EPS 1e-5f

typedef __attribute__((ext_vector_type(8))) short s16x8;
typedef __attribute__((ext_vector_type(16))) float f32x16;

__device__ __forceinline__ unsigned short f2bf(float f) {
    unsigned int u = __float_as_uint(f);
    u += 0x7fffu + ((u >> 16) & 1u);
    return (unsigned short)(u >> 16);
}

// async global->LDS 16B: LDS dest = wave-uniform base + lane*16
__device__ __forceinline__ void ldg_lds16(const void* g, void* l) {
    __builtin_amdgcn_global_load_lds((const __attribute__((address_space(1))) unsigned int*)g,
                                     (__attribute__((address_space(3))) unsigned int*)l, 16, 0, 0);
}

// ---------------- per-channel mean & max ----------------
__global__ void reduce_kernel(const float* __restrict__ x,
                              float* __restrict__ avg, float* __restrict__ mx) {
    int c = blockIdx.x;
    const float* xc = x + (size_t)c * NPIX;
    float s = 0.f, m = -INFINITY;
    for (int p = threadIdx.x; p < NPIX; p += 256) {
        float v = xc[p];
        s += v;
        m = fmaxf(m, v);
    }
    __shared__ float ss[256], sm[256];
    ss[threadIdx.x] = s; sm[threadIdx.x] = m;
    __syncthreads();
    for (int o = 128; o > 0; o >>= 1) {
        if (threadIdx.x < o) {
            ss[threadIdx.x] += ss[threadIdx.x + o];
            sm[threadIdx.x] = fmaxf(sm[threadIdx.x], sm[threadIdx.x + o]);
        }
        __syncthreads();
    }
    if (threadIdx.x == 0) {
        avg[c] = ss[0] / (float)NPIX;
        mx[c]  = sm[0];
    }
}

// ---------------- MLP + sigmoid + top-K selection ----------------
__global__ void mlp_select_kernel(const float* __restrict__ avg,
                                  const float* __restrict__ mx,
                                  const float* __restrict__ w_fc1,
                                  const float* __restrict__ w_fc2,
                                  float* __restrict__ scales_out,
                                  int* __restrict__ idx,
                                  int* __restrict__ pos) {
    __shared__ float s_avg[C], s_mx[C], s_h[K], s_scales[C];
    __shared__ int s_sel[C];
    int t = threadIdx.x;
    s_avg[t] = avg[t];
    s_mx[t]  = mx[t];
    __syncthreads();
    if (t < K) {
        float ha = 0.f, hm = 0.f;
        const float4* wr = (const float4*)(w_fc1 + (size_t)t * C);
        for (int c = 0; c < C / 4; c++) {
            float4 w = wr[c];
            ha += s_avg[4*c]*w.x + s_avg[4*c+1]*w.y + s_avg[4*c+2]*w.z + s_avg[4*c+3]*w.w;
            hm += s_mx[4*c]*w.x + s_mx[4*c+1]*w.y + s_mx[4*c+2]*w.z + s_mx[4*c+3]*w.w;
        }
        s_h[t] = fmaxf(ha, 0.f) + fmaxf(hm, 0.f);
    }
    __syncthreads();
    {
        float o = 0.f;
        const float4* wr = (const float4*)(w_fc2 + (size_t)t * K);
        for (int k = 0; k < K / 4; k++) {
            float4 w = wr[k];
            o += s_h[4*k]*w.x + s_h[4*k+1]*w.y + s_h[4*k+2]*w.z + s_h[4*k+3]*w.w;
        }
        float sc = 1.f / (1.f + expf(-o));
        s_scales[t] = sc;
        scales_out[t] = sc;
    }
    __syncthreads();
    {
        float v = s_scales[t];
        int rank = 0;
        for (int i = 0; i < C; i++) {
            float u = s_scales[i];
            rank += (u > v) || (u == v && i < t);
        }
        s_sel[t] = (rank < K) ? 1 : 0;
    }
    __syncthreads();
    {
        int p = 0;
        for (int i = 0; i < t; i++) p += s_sel[i];
        if (s_sel[t]) { idx[p] = t; pos[t] = p; }
        else pos[t] = -1;
    }
}

// ---------------- per-co affine for BN2 + bias fold ----------------
__global__ void affine_kernel(const float* __restrict__ b_dc1,
                              const float* __restrict__ g2, const float* __restrict__ b2,
                              const float* __restrict__ m2, const float* __restrict__ v2,
                              float* __restrict__ scale2, float* __restrict__ shift2) {
    int c = threadIdx.x;
    float s = g2[c] * rsqrtf(v2[c] + EPS);
    scale2[c] = s;
    shift2[c] = (b_dc1[c] - m2[c]) * s + b2[c];
}

// ---------------- combined 1x1 weight (768 eff. K) in bf16 ----------------
__global__ void wa_bf16_kernel(const float* __restrict__ w_dc1,
                               const float* __restrict__ scales,
                               const int* __restrict__ pos,
                               unsigned short* __restrict__ wA) {
    int co = blockIdx.x;
    const float* wr = w_dc1 + (size_t)co * 1024;
    for (int c = threadIdx.x; c < 768; c += 256) {
        float v;
        if (c < 512) {
            v = wr[c] * scales[c];
            int pp = pos[c];
            if (pp >= 0) v += wr[512 + pp];
        } else {
            v = wr[768 + (c - 512)];
        }
        wA[(size_t)co * 768 + c] = f2bf(v);
    }
}

// ---------------- repack conv3 weights: [co][ci][t] -> [t][co][ci] bf16 ----
__global__ void w3_kernel(const float* __restrict__ w_dc2, unsigned short* __restrict__ w3) {
    int co = blockIdx.x, t = blockIdx.y;
    for (int ci = threadIdx.x; ci < 512; ci += 256) {
        w3[((size_t)t * 512 + co) * 512 + ci] = f2bf(w_dc2[((size_t)co * 512 + ci) * 9 + t]);
    }
}

// ---------------- depthwise 3x3 + BN1 + ReLU -> x2 (fp32) ----------------
__global__ void dw_kernel(const float* __restrict__ x,
                          const int* __restrict__ idx,
                          const float* __restrict__ wch,
                          const float* __restrict__ g1,
                          const float* __restrict__ b1,
                          const float* __restrict__ m1,
                          const float* __restrict__ v1,
                          float* __restrict__ x2) {
    int k = blockIdx.y;
    int p = blockIdx.x * 256 + threadIdx.x;
    int c = idx[k];
    int y = p / HW, xx = p % HW;
    const float* xc = x + (size_t)c * NPIX;
    const float* wk = wch + k * 9;
    float acc = 0.f;
#pragma unroll
    for (int dy = 0; dy < 3; dy++) {
        int yy = y + dy - 1;
        if (yy < 0 || yy >= HW) continue;
#pragma unroll
        for (int dx = 0; dx < 3; dx++) {
            int xv = xx + dx - 1;
            if (xv < 0 || xv >= HW) continue;
            acc += xc[yy * HW + xv] * wk[dy * 3 + dx];
        }
    }
    float s = g1[k] * rsqrtf(v1[k] + EPS);
    float t = (acc - m1[k]) * s + b1[k];
    x2[(size_t)k * NPIX + p] = fmaxf(t, 0.f);
}

// ---------------- transpose x (512ch) and x2 (256ch) -> xcat_t[px][768] bf16 ----
__global__ void transpose_kernel(const float* __restrict__ x, const float* __restrict__ x2,
                                 unsigned short* __restrict__ xcat) {
    __shared__ float tile[32][33];
    int tx = threadIdx.x & 31, ty = threadIdx.x >> 5;
    int pbase = blockIdx.x * 32, cbase = blockIdx.y * 32;
#pragma unroll
    for (int j = 0; j < 4; j++) {
        int c = cbase + ty + j * 8;
        float v = (c < 512) ? x[(size_t)c * NPIX + pbase + tx]
                            : x2[(size_t)(c - 512) * NPIX + pbase + tx];
        tile[ty + j * 8][tx] = v;
    }
    __syncthreads();
#pragma unroll
    for (int j = 0; j < 4; j++) {
        int p = pbase + ty + j * 8;
        xcat[(size_t)p * 768 + cbase + tx] = f2bf(tile[tx][ty + j * 8]);
    }
}

// ---------------- zero only the hpad border (644 padded pixels) ----------------
__global__ void zero_border(unsigned short* __restrict__ hpad) {
    int t = blockIdx.x * 256 + threadIdx.x;   // 161*256 = 41216 = 644 px * 64 uint4
    int pix = t >> 6;
    int pos;
    if (pix < 162)      pos = pix;                         // row 0
    else if (pix < 324) pos = 161 * PW + (pix - 162);      // row 161
    else {
        int r = pix - 324;                                  // cols 0/161, rows 1..160
        pos = (1 + (r >> 1)) * PW + ((r & 1) ? 161 : 0);
    }
    *(uint4*)&hpad[(size_t)pos * 512 + (t & 63) * 8] = make_uint4(0u, 0u, 0u, 0u);
}

// ---------------- conv1 (1x1, K=768), 32x32x16 MFMA, dbuf global_load_lds ----
// block = 128 thr (2 waves); wave tile = 160 px x 64 co; grid (160, 4)
__global__ __launch_bounds__(128, 2) void conv1_mfma(const unsigned short* __restrict__ xcat,
        const unsigned short* __restrict__ wA,
        const float* __restrict__ scale2, const float* __restrict__ shift2,
        unsigned short* __restrict__ hpad) {
    __shared__ unsigned short Al[2][640 * 8];   // 160 px x 32 ch
    __shared__ unsigned short Bl[2][512 * 8];   // 128 co x 32 ch
    int y = blockIdx.x, co0 = blockIdx.y * 128;
    int tid = threadIdx.x, lane = tid & 63, wv = tid >> 6;
    int l31 = lane & 31, q = lane >> 5;
    f32x16 acc[5][2] = {};
    int svA = tid >> 2, sjA = tid & 3;
    int sgA = sjA ^ ((svA >> 1) & 3);        // global granule to fetch (write-side swizzle)

    const unsigned short* arow = xcat + ((size_t)y * HW) * 768;
    const unsigned short* brow = wA + (size_t)co0 * 768;

    // prologue: stage phase 0 into buf 0
    {
#pragma unroll
        for (int r = 0; r < 5; r++)
            ldg_lds16(arow + (size_t)(r * 32 + svA) * 768 + sgA * 8, &Al[0][(r * 128 + wv * 64) * 8]);
#pragma unroll
        for (int r = 0; r < 4; r++)
            ldg_lds16(brow + (size_t)(r * 32 + svA) * 768 + sgA * 8, &Bl[0][(r * 128 + wv * 64) * 8]);
    }
    __syncthreads();
    for (int ph = 0; ph < 24; ph++) {
        int p = ph & 1;
        // issue next phase's loads into the other buffer (overlap with MFMA below)
        if (ph < 23) {
            int kc = (ph + 1) * 32;
#pragma unroll
            for (int r = 0; r < 5; r++)
                ldg_lds16(arow + (size_t)(r * 32 + svA) * 768 + kc + sgA * 8,
                          &Al[p ^ 1][(r * 128 + wv * 64) * 8]);
#pragma unroll
            for (int r = 0; r < 4; r++)
                ldg_lds16(brow + (size_t)(r * 32 + svA) * 768 + kc + sgA * 8,
                          &Bl[p ^ 1][(r * 128 + wv * 64) * 8]);
        }
        // compute on buf p
#pragma unroll
        for (int s = 0; s < 2; s++) {
            int g0 = s * 2 + q;
            s16x8 bf[2], af[5];
            const char* bbase = (const char*)Bl[p] + wv * 4096 + l31 * 64 + ((g0 ^ ((l31 >> 1) & 3)) << 4);
#pragma unroll
            for (int j = 0; j < 2; j++) bf[j] = *(const s16x8*)(bbase + j * 2048);
            const char* abase = (const char*)Al[p] + l31 * 64 + ((g0 ^ ((l31 >> 1) & 3)) << 4);
#pragma unroll
            for (int i = 0; i < 5; i++) af[i] = *(const s16x8*)(abase + i * 2048);
#pragma unroll
            for (int i = 0; i < 5; i++)
#pragma unroll
                for (int j = 0; j < 2; j++)
                    acc[i][j] = __builtin_amdgcn_mfma_f32_32x32x16_bf16(af[i], bf[j], acc[i][j], 0, 0, 0);
        }
        __syncthreads();   // compiler-emitted vmcnt(0) drains this phase's prefetch
    }
    // epilogue: C/D layout col=lane&31, row=(reg&3)+8*(reg>>2)+4*q
#pragma unroll
    for (int j = 0; j < 2; j++) {
        int co = co0 + wv * 64 + j * 32 + l31;
        float s2 = scale2[co], sh = shift2[co];
#pragma unroll
        for (int i = 0; i < 5; i++) {
#pragma unroll
            for (int rg = 0; rg < 4; rg++) {
#pragma unroll
                for (int t = 0; t < 4; t++) {
                    int px = i * 32 + t + rg * 8 + q * 4;
                    size_t pp = (size_t)(y + 1) * PW + px + 1;
                    hpad[pp * 512 + co] = f2bf(acc[i][j][rg * 4 + t] * s2 + sh);
                }
            }
        }
    }
}

// ---------------- conv3 (3x3, K=4608), 32x32x16 MFMA, dbuf global_load_lds ----
// block = 128 thr (2 waves); wave tile = 160 px x 64 co; grid (160, 4)
__global__ __launch_bounds__(128, 2) void conv3_mfma(const unsigned short* __restrict__ hpad,
        const unsigned short* __restrict__ w3,
        const float* __restrict__ bias, float* __restrict__ out) {
    __shared__ unsigned short Al[2][648 * 8];    // 162 px x 32 ch
    __shared__ unsigned short Bl[2][1536 * 8];   // 3 dx x 128 co x 32 ch
    int y = blockIdx.x, co0 = blockIdx.y * 128;
    int tid = threadIdx.x, lane = tid & 63, wv = tid >> 6;
    int l31 = lane & 31, q = lane >> 5;
    f32x16 acc[5][2] = {};
    int svA = tid >> 2, sjA = tid & 3;
    int sgA = sjA ^ ((svA >> 1) & 3);

    // stage phase ph (= dy*16 + kc16) into buffer buf
    auto stage = [&](int ph, int buf) {
        int dy = ph >> 4, kc = (ph & 15) * 32;
        const unsigned short* ab = hpad + ((size_t)(y + dy) * PW) * 512 + kc;
#pragma unroll
        for (int r = 0; r < 6; r++) {
            int gi = r * 128 + tid;
            if (gi < 648)
                ldg_lds16(ab + (size_t)(r * 32 + svA) * 512 + sgA * 8,
                          &Al[buf][(r * 128 + wv * 64) * 8]);
        }
        const unsigned short* bb = w3 + ((size_t)(dy * 3) * 512 + co0) * 512 + kc;
#pragma unroll
        for (int r = 0; r < 12; r++) {
            int tt = r >> 2, co = (r & 3) * 32 + svA;
            ldg_lds16(bb + ((size_t)tt * 512 + co) * 512 + sgA * 8,
                      &Bl[buf][(r * 128 + wv * 64) * 8]);
        }
    };

    stage(0, 0);
    __syncthreads();
    for (int ph = 0; ph < 48; ph++) {
        int p = ph & 1;
        if (ph < 47) stage(ph + 1, p ^ 1);   // in flight during compute
        // compute on buf p: 3 dx x 2 k16 x (5 A x 2 B)
#pragma unroll
        for (int dx = 0; dx < 3; dx++) {
#pragma unroll
            for (int s = 0; s < 2; s++) {
                int g0 = s * 2 + q;
                s16x8 bf[2], af[5];
                const char* bbase = (const char*)Bl[p] + dx * 8192 + wv * 4096 + l31 * 64
                                    + ((g0 ^ ((l31 >> 1) & 3)) << 4);
#pragma unroll
                for (int j = 0; j < 2; j++) bf[j] = *(const s16x8*)(bbase + j * 2048);
                int pl = dx + l31;
                const char* abase = (const char*)Al[p] + pl * 64
                                    + ((g0 ^ ((pl >> 1) & 3)) << 4);
#pragma unroll
                for (int i = 0; i < 5; i++) af[i] = *(const s16x8*)(abase + i * 2048);
#pragma unroll
                for (int i = 0; i < 5; i++)
#pragma unroll
                    for (int j = 0; j < 2; j++)
                        acc[i][j] = __builtin_amdgcn_mfma_f32_32x32x16_bf16(af[i], bf[j], acc[i][j], 0, 0, 0);
            }
        }
        __syncthreads();   // drains this phase's prefetch vmcnt
    }
    // epilogue: float4 stores
#pragma unroll
    for (int j = 0; j < 2; j++) {
        int co = co0 + wv * 64 + j * 32 + l31;
        float b = bias[co];
        float* op = out + (size_t)co * NPIX + y * HW;
#pragma unroll
        for (int i = 0; i < 5; i++) {
#pragma unroll
            for (int rg = 0; rg < 4; rg++) {
                int px = i * 32 + rg * 8 + q * 4;
                float4 v;
                v.x = fmaxf(acc[i][j][rg * 4 + 0] + b, 0.f);
                v.y = fmaxf(acc[i][j][rg * 4 + 1] + b, 0.f);
                v.z = fmaxf(acc[i][j][rg * 4 + 2] + b, 0.f);
                v.w = fmaxf(acc[i][j][rg * 4 + 3] + b, 0.f);
                *(float4*)&op[px] = v;
            }
        }
    }
}

extern "C" void kernel_launch(void* const* d_in, const int* in_sizes, int n_in,
                              void* d_out, int out_size, void* d_ws, size_t ws_size,
                              hipStream_t stream) {
    const float* x      = (const float*)d_in[0];
    const float* w_fc1  = (const float*)d_in[1];
    const float* w_fc2  = (const float*)d_in[2];
    const float* w_ch   = (const float*)d_in[3];
    const float* bn1_g  = (const float*)d_in[4];
    const float* bn1_b  = (const float*)d_in[5];
    const float* bn1_m  = (const float*)d_in[6];
    const float* bn1_v  = (const float*)d_in[7];
    const float* w_dc1  = (const float*)d_in[8];
    const float* b_dc1  = (const float*)d_in[9];
    const float* bn2_g  = (const float*)d_in[10];
    const float* bn2_b  = (const float*)d_in[11];
    const float* bn2_m  = (const float*)d_in[12];
    const float* bn2_v  = (const float*)d_in[13];
    const float* w_dc2  = (const float*)d_in[14];
    const float* b_dc2  = (const float*)d_in[15];
    float* out = (float*)d_out;

    char* ws = (char*)d_ws;
    float* avg    = (float*)(ws + 0);
    float* mx     = (float*)(ws + 2048);
    float* scales = (float*)(ws + 4096);
    int*   idx    = (int*)  (ws + 6144);
    int*   pos    = (int*)  (ws + 7168);
    float* scale2 = (float*)(ws + 9216);
    float* shift2 = (float*)(ws + 11264);
    unsigned short* wA   = (unsigned short*)(ws + 16384);              // 512*768*2  = 786432
    unsigned short* w3   = (unsigned short*)(ws + 802816);             // 9*512*512*2 = 4718592
    float*          x2   = (float*)         (ws + 5521408);            // 256*25600*4 = 26214400
    unsigned short* xcat = (unsigned short*)(ws + 31735808);           // 25600*768*2 = 39321600
    unsigned short* hpad = (unsigned short*)(ws + 71057408);           // 162*162*512*2 = 26873856

    reduce_kernel<<<C, 256, 0, stream>>>(x, avg, mx);
    mlp_select_kernel<<<1, C, 0, stream>>>(avg, mx, w_fc1, w_fc2, scales, idx, pos);
    affine_kernel<<<1, C, 0, stream>>>(b_dc1, bn2_g, bn2_b, bn2_m, bn2_v, scale2, shift2);
    wa_bf16_kernel<<<C, 256, 0, stream>>>(w_dc1, scales, pos, wA);
    w3_kernel<<<dim3(C, 9), 256, 0, stream>>>(w_dc2, w3);
    zero_border<<<161, 256, 0, stream>>>(hpad);
    dw_kernel<<<dim3(NPIX / 256, K), 256, 0, stream>>>(x, idx, w_ch, bn1_g, bn1_b, bn1_m, bn1_v, x2);
    transpose_kernel<<<dim3(NPIX / 32, 24), 256, 0, stream>>>(x, x2, xcat);
    conv1_mfma<<<dim3(HW, 4), 128, 0, stream>>>(xcat, wA, scale2, shift2, hpad);
    conv3_mfma<<<dim3(HW, 4), 128, 0, stream>>>(hpad, w3, b_dc2, out);
}

// Round 7
// 451.535 us; speedup vs baseline: 1.1821x; 1.1821x over previous
//
#include <hip/hip_runtime.h>
#include <math.h>

#define C 512
#define K 256
#define HW 160
#define NPIX (HW*HW)   // 25600
#define PW 162
#define EPS 1e-5f

typedef __attribute__((ext_vector_type(8))) short s16x8;
typedef __attribute__((ext_vector_type(16))) float f32x16;

__device__ __forceinline__ unsigned short f2bf(float f) {
    unsigned int u = __float_as_uint(f);
    u += 0x7fffu + ((u >> 16) & 1u);
    return (unsigned short)(u >> 16);
}

// async global->LDS 16B: LDS dest = wave-uniform base + lane*16
__device__ __forceinline__ void ldg_lds16(const void* g, void* l) {
    __builtin_amdgcn_global_load_lds((const __attribute__((address_space(1))) unsigned int*)g,
                                     (__attribute__((address_space(3))) unsigned int*)l, 16, 0, 0);
}

// explicit ordering fences for the no-barrier DMA pipeline (single-wave blocks)
#define WAIT_VM0()  asm volatile("s_waitcnt vmcnt(0)" ::: "memory")
#define WAIT_LGKM0() asm volatile("s_waitcnt lgkmcnt(0)" ::: "memory")

// ---------------- per-channel mean & max ----------------
__global__ void reduce_kernel(const float* __restrict__ x,
                              float* __restrict__ avg, float* __restrict__ mx) {
    int c = blockIdx.x;
    const float4* xc = (const float4*)(x + (size_t)c * NPIX);
    float s = 0.f, m = -INFINITY;
    for (int p = threadIdx.x; p < NPIX / 4; p += 256) {
        float4 v = xc[p];
        s += v.x + v.y + v.z + v.w;
        m = fmaxf(m, fmaxf(fmaxf(v.x, v.y), fmaxf(v.z, v.w)));
    }
    __shared__ float ss[256], sm[256];
    ss[threadIdx.x] = s; sm[threadIdx.x] = m;
    __syncthreads();
    for (int o = 128; o > 0; o >>= 1) {
        if (threadIdx.x < o) {
            ss[threadIdx.x] += ss[threadIdx.x + o];
            sm[threadIdx.x] = fmaxf(sm[threadIdx.x], sm[threadIdx.x + o]);
        }
        __syncthreads();
    }
    if (threadIdx.x == 0) {
        avg[c] = ss[0] / (float)NPIX;
        mx[c]  = sm[0];
    }
}

// ---------------- MLP + sigmoid + top-K selection ----------------
__global__ void mlp_select_kernel(const float* __restrict__ avg,
                                  const float* __restrict__ mx,
                                  const float* __restrict__ w_fc1,
                                  const float* __restrict__ w_fc2,
                                  float* __restrict__ scales_out,
                                  int* __restrict__ idx,
                                  int* __restrict__ pos) {
    __shared__ float s_avg[C], s_mx[C], s_h[K], s_scales[C];
    __shared__ int s_sel[C];
    int t = threadIdx.x;
    s_avg[t] = avg[t];
    s_mx[t]  = mx[t];
    __syncthreads();
    if (t < K) {
        float ha = 0.f, hm = 0.f;
        const float4* wr = (const float4*)(w_fc1 + (size_t)t * C);
        for (int c = 0; c < C / 4; c++) {
            float4 w = wr[c];
            ha += s_avg[4*c]*w.x + s_avg[4*c+1]*w.y + s_avg[4*c+2]*w.z + s_avg[4*c+3]*w.w;
            hm += s_mx[4*c]*w.x + s_mx[4*c+1]*w.y + s_mx[4*c+2]*w.z + s_mx[4*c+3]*w.w;
        }
        s_h[t] = fmaxf(ha, 0.f) + fmaxf(hm, 0.f);
    }
    __syncthreads();
    {
        float o = 0.f;
        const float4* wr = (const float4*)(w_fc2 + (size_t)t * K);
        for (int k = 0; k < K / 4; k++) {
            float4 w = wr[k];
            o += s_h[4*k]*w.x + s_h[4*k+1]*w.y + s_h[4*k+2]*w.z + s_h[4*k+3]*w.w;
        }
        float sc = 1.f / (1.f + expf(-o));
        s_scales[t] = sc;
        scales_out[t] = sc;
    }
    __syncthreads();
    {
        float v = s_scales[t];
        int rank = 0;
        for (int i = 0; i < C; i++) {
            float u = s_scales[i];
            rank += (u > v) || (u == v && i < t);
        }
        s_sel[t] = (rank < K) ? 1 : 0;
    }
    __syncthreads();
    {
        int p = 0;
        for (int i = 0; i < t; i++) p += s_sel[i];
        if (s_sel[t]) { idx[p] = t; pos[t] = p; }
        else pos[t] = -1;
    }
}

// ---------------- fused prep: w3 repack + wA + zero border + affine ----------------
__global__ void prep_kernel(const float* __restrict__ w_dc2, unsigned short* __restrict__ w3,
                            const float* __restrict__ w_dc1, const float* __restrict__ scales,
                            const int* __restrict__ pos, unsigned short* __restrict__ wA,
                            unsigned short* __restrict__ hpad,
                            const float* __restrict__ b_dc1,
                            const float* __restrict__ g2, const float* __restrict__ b2,
                            const float* __restrict__ m2, const float* __restrict__ v2,
                            float* __restrict__ scale2, float* __restrict__ shift2) {
    int b = blockIdx.x;
    if (b < 4608) {                      // w3: [co][ci][t] -> [t][co][ci]
        int t = b >> 9, co = b & 511;
        for (int ci = threadIdx.x; ci < 512; ci += 256)
            w3[((size_t)t * 512 + co) * 512 + ci] = f2bf(w_dc2[((size_t)co * 512 + ci) * 9 + t]);
    } else if (b < 5120) {               // wA combined 1x1 weight
        int co = b - 4608;
        const float* wr = w_dc1 + (size_t)co * 1024;
        for (int c = threadIdx.x; c < 768; c += 256) {
            float v;
            if (c < 512) {
                v = wr[c] * scales[c];
                int pp = pos[c];
                if (pp >= 0) v += wr[512 + pp];
            } else {
                v = wr[768 + (c - 512)];
            }
            wA[(size_t)co * 768 + c] = f2bf(v);
        }
    } else if (b < 5281) {               // zero hpad border
        int t = (b - 5120) * 256 + threadIdx.x;
        int pix = t >> 6;
        int p;
        if (pix < 162)      p = pix;
        else if (pix < 324) p = 161 * PW + (pix - 162);
        else {
            int r = pix - 324;
            p = (1 + (r >> 1)) * PW + ((r & 1) ? 161 : 0);
        }
        *(uint4*)&hpad[(size_t)p * 512 + (t & 63) * 8] = make_uint4(0u, 0u, 0u, 0u);
    } else {                             // affine (BN2 + bias fold)
        for (int c = threadIdx.x; c < C; c += 256) {
            float s = g2[c] * rsqrtf(v2[c] + EPS);
            scale2[c] = s;
            shift2[c] = (b_dc1[c] - m2[c]) * s + b2[c];
        }
    }
}

// ---------------- dw 3x3 + BN1 + ReLU, written transposed into xcat[.,512+k] ----
// grid (800, 8), block 256; tile = 32 px (one y-row) x 32 k
__global__ void dw_t_kernel(const float* __restrict__ x,
                            const int* __restrict__ idx,
                            const float* __restrict__ wch,
                            const float* __restrict__ g1, const float* __restrict__ b1,
                            const float* __restrict__ m1, const float* __restrict__ v1,
                            unsigned short* __restrict__ xcat) {
    __shared__ float tile[32][33];
    int tx = threadIdx.x & 31, ty = threadIdx.x >> 5;
    int pbase = blockIdx.x * 32, kbase = blockIdx.y * 32;
    int y = pbase / HW, x0 = pbase % HW;
    int px = x0 + tx;
#pragma unroll
    for (int jj = 0; jj < 4; jj++) {
        int k = kbase + ty + jj * 8;
        int c = idx[k];
        const float* xc = x + (size_t)c * NPIX;
        const float* wk = wch + k * 9;
        float acc = 0.f;
#pragma unroll
        for (int dy = 0; dy < 3; dy++) {
            int yy = y + dy - 1;
            if (yy < 0 || yy >= HW) continue;
#pragma unroll
            for (int dx = 0; dx < 3; dx++) {
                int xv = px + dx - 1;
                if (xv < 0 || xv >= HW) continue;
                acc += xc[yy * HW + xv] * wk[dy * 3 + dx];
            }
        }
        float s = g1[k] * rsqrtf(v1[k] + EPS);
        tile[ty + jj * 8][tx] = fmaxf((acc - m1[k]) * s + b1[k], 0.f);
    }
    __syncthreads();
#pragma unroll
    for (int jj = 0; jj < 4; jj++) {
        int p = pbase + ty + jj * 8;
        xcat[(size_t)p * 768 + 512 + kbase + tx] = f2bf(tile[tx][ty + jj * 8]);
    }
}

// ---------------- transpose x (512 ch only) -> xcat[.,0:512] bf16 ----------------
__global__ void transpose_kernel(const float* __restrict__ x,
                                 unsigned short* __restrict__ xcat) {
    __shared__ float tile[32][33];
    int tx = threadIdx.x & 31, ty = threadIdx.x >> 5;
    int pbase = blockIdx.x * 32, cbase = blockIdx.y * 32;
#pragma unroll
    for (int j = 0; j < 4; j++) {
        int c = cbase + ty + j * 8;
        tile[ty + j * 8][tx] = x[(size_t)c * NPIX + pbase + tx];
    }
    __syncthreads();
#pragma unroll
    for (int j = 0; j < 4; j++) {
        int p = pbase + ty + j * 8;
        xcat[(size_t)p * 768 + cbase + tx] = f2bf(tile[tx][ty + j * 8]);
    }
}

// ---------------- conv1 (1x1, K=768): 1-wave blocks, explicit waitcnt pipeline ----
// grid (160, 8); block 64; wave tile 160 px x 64 co
__global__ __launch_bounds__(64, 1) void conv1_mfma(const unsigned short* __restrict__ xcat,
        const unsigned short* __restrict__ wA,
        const float* __restrict__ scale2, const float* __restrict__ shift2,
        unsigned short* __restrict__ hpad) {
    __shared__ unsigned short Al[2][640 * 8];   // 160 px x 32 ch
    __shared__ unsigned short Bl[2][256 * 8];   // 64 co x 32 ch
    int y = blockIdx.x, co0 = blockIdx.y * 64;
    int lane = threadIdx.x;
    int l31 = lane & 31, q = lane >> 5;
    f32x16 acc[5][2] = {};

    // loop-invariant staging offsets (element units)
    int aoff[10], boff[4];
#pragma unroll
    for (int r = 0; r < 10; r++) {
        int g = r * 64 + lane;
        int px = g >> 2, jg = (g & 3) ^ ((px >> 1) & 3);
        aoff[r] = px * 768 + jg * 8;
    }
#pragma unroll
    for (int r = 0; r < 4; r++) {
        int g = r * 64 + lane;
        int co = g >> 2, jg = (g & 3) ^ ((co >> 1) & 3);
        boff[r] = co * 768 + jg * 8;
    }
    // compute-read byte offsets
    int raoff[2];
#pragma unroll
    for (int s = 0; s < 2; s++)
        raoff[s] = l31 * 64 + (((s * 2 + q) ^ ((l31 >> 1) & 3)) << 4);
    const unsigned short* arow = xcat + (size_t)y * HW * 768;
    const unsigned short* brow = wA + (size_t)co0 * 768;

    // prologue: stage phase 0 into buf 0
#pragma unroll
    for (int r = 0; r < 10; r++) ldg_lds16(arow + aoff[r], &Al[0][r * 512]);
#pragma unroll
    for (int r = 0; r < 4; r++)  ldg_lds16(brow + boff[r], &Bl[0][r * 512]);

    for (int ph = 0; ph < 24; ph++) {
        const unsigned short* Ar = Al[ph & 1];
        const unsigned short* Br = Bl[ph & 1];
        WAIT_VM0();   // RAW: DMA for this buffer (issued last phase) has landed
        s16x8 af[5][2], bf[2][2];
#pragma unroll
        for (int s = 0; s < 2; s++) {
#pragma unroll
            for (int i = 0; i < 5; i++)
                af[i][s] = *(const s16x8*)((const char*)Ar + i * 2048 + raoff[s]);
#pragma unroll
            for (int j = 0; j < 2; j++)
                bf[j][s] = *(const s16x8*)((const char*)Br + j * 2048 + raoff[s]);
        }
        WAIT_LGKM0();  // WAR: all LDS reads drained into regs before DMA may overwrite
        if (ph < 23) {
            int kc = (ph + 1) * 32;
            unsigned short* An = Al[(ph + 1) & 1];
            unsigned short* Bn = Bl[(ph + 1) & 1];
#pragma unroll
            for (int r = 0; r < 10; r++) ldg_lds16(arow + kc + aoff[r], &An[r * 512]);
#pragma unroll
            for (int r = 0; r < 4; r++)  ldg_lds16(brow + kc + boff[r], &Bn[r * 512]);
        }
#pragma unroll
        for (int s = 0; s < 2; s++)
#pragma unroll
            for (int i = 0; i < 5; i++)
#pragma unroll
                for (int j = 0; j < 2; j++)
                    acc[i][j] = __builtin_amdgcn_mfma_f32_32x32x16_bf16(af[i][s], bf[j][s], acc[i][j], 0, 0, 0);
    }
    // epilogue: C/D layout col=lane&31, row=(reg&3)+8*(reg>>2)+4*q
#pragma unroll
    for (int j = 0; j < 2; j++) {
        int co = co0 + j * 32 + l31;
        float s2 = scale2[co], sh = shift2[co];
#pragma unroll
        for (int i = 0; i < 5; i++) {
#pragma unroll
            for (int rg = 0; rg < 4; rg++) {
#pragma unroll
                for (int t = 0; t < 4; t++) {
                    int px = i * 32 + t + rg * 8 + q * 4;
                    size_t pp = (size_t)(y + 1) * PW + px + 1;
                    hpad[pp * 512 + co] = f2bf(acc[i][j][rg * 4 + t] * s2 + sh);
                }
            }
        }
    }
}

// ---------------- conv3 (3x3, K=4608): 1-wave blocks, explicit waitcnt pipeline ----
// grid (160, 8); block 64; wave tile 160 px x 64 co
__global__ __launch_bounds__(64, 1) void conv3_mfma(const unsigned short* __restrict__ hpad,
        const unsigned short* __restrict__ w3,
        const float* __restrict__ bias, float* __restrict__ out) {
    __shared__ unsigned short Al[2][648 * 8];   // 162 px x 32 ch
    __shared__ unsigned short Bl[2][768 * 8];   // 3 dx x 64 co x 32 ch
    int y = blockIdx.x, co0 = blockIdx.y * 64;
    int lane = threadIdx.x;
    int l31 = lane & 31, q = lane >> 5;
    f32x16 acc[5][2] = {};

    int aoff[11], boff[12];
#pragma unroll
    for (int r = 0; r < 11; r++) {
        int g = r * 64 + lane;
        int px = g >> 2, jg = (g & 3) ^ ((px >> 1) & 3);
        aoff[r] = px * 512 + jg * 8;
    }
#pragma unroll
    for (int r = 0; r < 12; r++) {
        int g = r * 64 + lane;
        int tt = g >> 8, co = (g >> 2) & 63, jg = (g & 3) ^ ((co >> 1) & 3);
        boff[r] = (tt * 512 + co) * 512 + jg * 8;
    }
    int raoff[3][2], rboff[2];
#pragma unroll
    for (int dx = 0; dx < 3; dx++)
#pragma unroll
        for (int s = 0; s < 2; s++) {
            int m = l31 + dx;
            raoff[dx][s] = m * 64 + ((((s * 2 + q)) ^ ((m >> 1) & 3)) << 4);
        }
#pragma unroll
    for (int s = 0; s < 2; s++)
        rboff[s] = l31 * 64 + (((s * 2 + q) ^ ((l31 >> 1) & 3)) << 4);

    // stage phase ph (= dy*16 + kc16) into buffer buf
    auto stage = [&](int ph, int buf) {
        int dy = ph >> 4, kc = (ph & 15) * 32;
        const unsigned short* ab = hpad + ((size_t)(y + dy) * PW) * 512 + kc;
        unsigned short* An = Al[buf];
#pragma unroll
        for (int r = 0; r < 10; r++) ldg_lds16(ab + aoff[r], &An[r * 512]);
        if (lane < 8)                ldg_lds16(ab + aoff[10], &An[10 * 512]);
        const unsigned short* bb = w3 + ((size_t)(dy * 3) * 512 + co0) * 512 + kc;
        unsigned short* Bn = Bl[buf];
#pragma unroll
        for (int r = 0; r < 12; r++) ldg_lds16(bb + boff[r], &Bn[r * 512]);
    };

    stage(0, 0);
    for (int ph = 0; ph < 48; ph++) {
        const unsigned short* Ar = Al[ph & 1];
        const unsigned short* Br = Bl[ph & 1];
        WAIT_VM0();   // RAW: this buffer's DMA (issued one MFMA-block ago) has landed
        s16x8 af[3][5][2], bf[3][2][2];
#pragma unroll
        for (int dx = 0; dx < 3; dx++) {
#pragma unroll
            for (int s = 0; s < 2; s++) {
#pragma unroll
                for (int i = 0; i < 5; i++)
                    af[dx][i][s] = *(const s16x8*)((const char*)Ar + i * 2048 + raoff[dx][s]);
#pragma unroll
                for (int j = 0; j < 2; j++)
                    bf[dx][j][s] = *(const s16x8*)((const char*)Br + dx * 4096 + j * 2048 + rboff[s]);
            }
        }
        WAIT_LGKM0();  // WAR: LDS reads drained before next DMA may overwrite other buffer
        if (ph < 47) stage(ph + 1, (ph + 1) & 1);
        // 60 MFMAs hide the in-flight DMA latency
#pragma unroll
        for (int dx = 0; dx < 3; dx++)
#pragma unroll
            for (int s = 0; s < 2; s++)
#pragma unroll
                for (int i = 0; i < 5; i++)
#pragma unroll
                    for (int j = 0; j < 2; j++)
                        acc[i][j] = __builtin_amdgcn_mfma_f32_32x32x16_bf16(af[dx][i][s], bf[dx][j][s], acc[i][j], 0, 0, 0);
    }
    // epilogue: float4 stores
#pragma unroll
    for (int j = 0; j < 2; j++) {
        int co = co0 + j * 32 + l31;
        float b = bias[co];
        float* op = out + (size_t)co * NPIX + y * HW;
#pragma unroll
        for (int i = 0; i < 5; i++) {
#pragma unroll
            for (int rg = 0; rg < 4; rg++) {
                int px = i * 32 + rg * 8 + q * 4;
                float4 v;
                v.x = fmaxf(acc[i][j][rg * 4 + 0] + b, 0.f);
                v.y = fmaxf(acc[i][j][rg * 4 + 1] + b, 0.f);
                v.z = fmaxf(acc[i][j][rg * 4 + 2] + b, 0.f);
                v.w = fmaxf(acc[i][j][rg * 4 + 3] + b, 0.f);
                *(float4*)&op[px] = v;
            }
        }
    }
}

extern "C" void kernel_launch(void* const* d_in, const int* in_sizes, int n_in,
                              void* d_out, int out_size, void* d_ws, size_t ws_size,
                              hipStream_t stream) {
    const float* x      = (const float*)d_in[0];
    const float* w_fc1  = (const float*)d_in[1];
    const float* w_fc2  = (const float*)d_in[2];
    const float* w_ch   = (const float*)d_in[3];
    const float* bn1_g  = (const float*)d_in[4];
    const float* bn1_b  = (const float*)d_in[5];
    const float* bn1_m  = (const float*)d_in[6];
    const float* bn1_v  = (const float*)d_in[7];
    const float* w_dc1  = (const float*)d_in[8];
    const float* b_dc1  = (const float*)d_in[9];
    const float* bn2_g  = (const float*)d_in[10];
    const float* bn2_b  = (const float*)d_in[11];
    const float* bn2_m  = (const float*)d_in[12];
    const float* bn2_v  = (const float*)d_in[13];
    const float* w_dc2  = (const float*)d_in[14];
    const float* b_dc2  = (const float*)d_in[15];
    float* out = (float*)d_out;

    char* ws = (char*)d_ws;
    float* avg    = (float*)(ws + 0);
    float* mx     = (float*)(ws + 2048);
    float* scales = (float*)(ws + 4096);
    int*   idx    = (int*)  (ws + 6144);
    int*   pos    = (int*)  (ws + 7168);
    float* scale2 = (float*)(ws + 9216);
    float* shift2 = (float*)(ws + 11264);
    unsigned short* wA   = (unsigned short*)(ws + 16384);              // 512*768*2  = 786432
    unsigned short* w3   = (unsigned short*)(ws + 802816);             // 9*512*512*2 = 4718592
    unsigned short* xcat = (unsigned short*)(ws + 31735808);           // 25600*768*2 = 39321600
    unsigned short* hpad = (unsigned short*)(ws + 71057408);           // 162*162*512*2 = 26873856

    reduce_kernel<<<C, 256, 0, stream>>>(x, avg, mx);
    mlp_select_kernel<<<1, C, 0, stream>>>(avg, mx, w_fc1, w_fc2, scales, idx, pos);
    prep_kernel<<<5282, 256, 0, stream>>>(w_dc2, w3, w_dc1, scales, pos, wA, hpad,
                                          b_dc1, bn2_g, bn2_b, bn2_m, bn2_v, scale2, shift2);
    dw_t_kernel<<<dim3(800, 8), 256, 0, stream>>>(x, idx, w_ch, bn1_g, bn1_b, bn1_m, bn1_v, xcat);
    transpose_kernel<<<dim3(800, 16), 256, 0, stream>>>(x, xcat);
    conv1_mfma<<<dim3(HW, 8), 64, 0, stream>>>(xcat, wA, scale2, shift2, hpad);
    conv3_mfma<<<dim3(HW, 8), 64, 0, stream>>>(hpad, w3, b_dc2, out);
}